// Round 5
// baseline (603.055 us; speedup 1.0000x reference)
//
#include <hip/hip_runtime.h>

// Decoder block: x -> LN1 -> QKV GEMM -> causal MHA -> proj(+x) -> LN2 -> FFN(+res)
// B=4 T=2048 C=1024 H=16 hd=64.  All MFMA compute in bf16, fp32 accumulate.

typedef __attribute__((ext_vector_type(8))) short shortx8;   // 8 bf16 (4 VGPR)
typedef __attribute__((ext_vector_type(4))) float floatx4;   // MFMA C/D

__device__ __forceinline__ short f2bf(float f) {
  unsigned u = __builtin_bit_cast(unsigned, f);
  u = (u + 0x7fffu + ((u >> 16) & 1u)) >> 16;   // RNE
  return (short)u;
}

// ---- weight transpose + cast: in [K][N] f32 -> out [N][K] bf16 ----
__global__ __launch_bounds__(256)
void transpose_cast(const float* __restrict__ in, short* __restrict__ out,
                    int K, int N) {
  __shared__ float tile[32][33];
  const int n0 = blockIdx.x * 32, k0 = blockIdx.y * 32;
  const int tx = threadIdx.x & 31, ty = threadIdx.x >> 5;  // 32x8
  for (int i = 0; i < 32; i += 8)
    tile[ty + i][tx] = in[(size_t)(k0 + ty + i) * N + n0 + tx];
  __syncthreads();
  for (int i = 0; i < 32; i += 8)
    out[(size_t)(n0 + ty + i) * K + k0 + tx] = f2bf(tile[tx][ty + i]);
}

// ---- layernorm: f32 in -> bf16 out, C=1024, one block (256 thr) per row ----
__global__ __launch_bounds__(256)
void layernorm_kernel(const float* __restrict__ x, const float* __restrict__ w,
                      const float* __restrict__ bta, short* __restrict__ out) {
  const int C = 1024;
  const int row = blockIdx.x;
  const float4 v = ((const float4*)(x + (size_t)row * C))[threadIdx.x];
  float s1 = v.x + v.y + v.z + v.w;
  float s2 = v.x * v.x + v.y * v.y + v.z * v.z + v.w * v.w;
  for (int m = 1; m < 64; m <<= 1) { s1 += __shfl_xor(s1, m); s2 += __shfl_xor(s2, m); }
  __shared__ float r1[4], r2[4];
  const int wid = threadIdx.x >> 6, lane = threadIdx.x & 63;
  if (lane == 0) { r1[wid] = s1; r2[wid] = s2; }
  __syncthreads();
  s1 = r1[0] + r1[1] + r1[2] + r1[3];
  s2 = r2[0] + r2[1] + r2[2] + r2[3];
  const float mean = s1 * (1.0f / C);
  const float var = s2 * (1.0f / C) - mean * mean;
  const float rs = rsqrtf(var + 1e-5f);
  const float4 wv = ((const float4*)w)[threadIdx.x];
  const float4 bv = ((const float4*)bta)[threadIdx.x];
  short4 o;
  o.x = f2bf((v.x - mean) * rs * wv.x + bv.x);
  o.y = f2bf((v.y - mean) * rs * wv.y + bv.y);
  o.z = f2bf((v.z - mean) * rs * wv.z + bv.z);
  o.w = f2bf((v.w - mean) * rs * wv.w + bv.w);
  *(short4*)(out + (size_t)row * C + threadIdx.x * 4) = o;
}

// ---- MFMA GEMM: C = A[M,K]@Bt[N,K]^T (+bias)(+resid)(+relu)
// 128x128 tile, BK=32, 4 waves of 64x64, global_load_lds width=16 staging.
// FLAGS: bit0=relu, bit1=resid(fp32), bit2=SPLITK (blockIdx.z picks K-slice;
// raw fp32 partial out, no bias).  lda/ldb = row strides of A / Bt.
template<int FLAGS, typename OutT>
__global__ __launch_bounds__(256)
void gemm_bt(const short* __restrict__ A, int lda,
             const short* __restrict__ Bt, int ldb,
             const float* __restrict__ bias, const float* __restrict__ resid,
             OutT* __restrict__ C, int M, int N, int K) {
  constexpr bool RELU = (FLAGS & 1) != 0;
  constexpr bool RESID = (FLAGS & 2) != 0;
  constexpr bool SPLITK = (FLAGS & 4) != 0;
  if constexpr (SPLITK) {
    const int z = blockIdx.z;
    A += (size_t)z * K;                // K-slice column offset
    Bt += (size_t)z * K;
    C += (size_t)z * M * N;            // partial plane
  }
  __shared__ short As[128 * 32];   // [m][k]
  __shared__ short Bs[128 * 32];   // [n][k]
  const int bm0 = blockIdx.y * 128, bn0 = blockIdx.x * 128;
  const int tid = threadIdx.x, wid = tid >> 6, lane = tid & 63;
  const int quad = lane >> 4, l15 = lane & 15;
  const int wm = wid & 1, wn = wid >> 1;
  const int srow = lane >> 2, scol = (lane & 3) * 8;
  floatx4 acc[4][4] = {};
  for (int k0 = 0; k0 < K; k0 += 32) {
    for (int i = 0; i < 2; ++i) {
      const int r0 = (wid * 2 + i) * 16;
      const short* ga = A + (size_t)(bm0 + r0 + srow) * lda + k0 + scol;
      const short* gb = Bt + (size_t)(bn0 + r0 + srow) * ldb + k0 + scol;
      __builtin_amdgcn_global_load_lds(
          (const __attribute__((address_space(1))) void*)ga,
          (__attribute__((address_space(3))) void*)&As[r0 * 32], 16, 0, 0);
      __builtin_amdgcn_global_load_lds(
          (const __attribute__((address_space(1))) void*)gb,
          (__attribute__((address_space(3))) void*)&Bs[r0 * 32], 16, 0, 0);
    }
    asm volatile("s_waitcnt vmcnt(0)" ::: "memory");
    __syncthreads();
    shortx8 af[4], bfr[4];
#pragma unroll
    for (int i = 0; i < 4; ++i)
      af[i] = *(const shortx8*)&As[(wm * 64 + i * 16 + l15) * 32 + quad * 8];
#pragma unroll
    for (int j = 0; j < 4; ++j)
      bfr[j] = *(const shortx8*)&Bs[(wn * 64 + j * 16 + l15) * 32 + quad * 8];
#pragma unroll
    for (int i = 0; i < 4; ++i)
#pragma unroll
      for (int j = 0; j < 4; ++j)
        acc[i][j] = __builtin_amdgcn_mfma_f32_16x16x32_bf16(af[i], bfr[j], acc[i][j], 0, 0, 0);
    __syncthreads();
  }
  // epilogue: D row = (lane>>4)*4 + reg, col = lane&15 (m89/m91-verified)
#pragma unroll
  for (int i = 0; i < 4; ++i) {
    const int row = bm0 + wm * 64 + i * 16 + quad * 4;
#pragma unroll
    for (int j = 0; j < 4; ++j) {
      const int col = bn0 + wn * 64 + j * 16 + l15;
      const float bb = SPLITK ? 0.0f : bias[col];
#pragma unroll
      for (int r = 0; r < 4; ++r) {
        float v = acc[i][j][r] + bb;
        if (RELU) v = fmaxf(v, 0.0f);
        if (RESID) v += resid[(size_t)(row + r) * N + col];
        if constexpr (sizeof(OutT) == 2)
          C[(size_t)(row + r) * N + col] = f2bf(v);
        else
          C[(size_t)(row + r) * N + col] = v;
      }
    }
  }
}

// sums the two ff2 K-partials + bias + residual (out holds x2) -> out
__global__ __launch_bounds__(256)
void ff2_reduce(const float* __restrict__ part, const float* __restrict__ bias,
                float* __restrict__ out) {
  const size_t i = ((size_t)blockIdx.x * 256 + threadIdx.x) * 4;
  const float4 a = *(const float4*)(part + i);
  const float4 b = *(const float4*)(part + (size_t)8192 * 1024 + i);
  float4 r = *(const float4*)(out + i);
  const float4 bb = *(const float4*)(bias + (i & 1023));
  r.x += a.x + b.x + bb.x;
  r.y += a.y + b.y + bb.y;
  r.z += a.z + b.z + bb.z;
  r.w += a.w + b.w + bb.w;
  *(float4*)(out + i) = r;
}

// ================= split-K flash attention =================
// Static-max softmax (scores = q.k/32, tiny; fp32 exp2 has huge headroom) makes
// chunk partials ADDITIVE: O_unnorm = sum P.V, lsum = sum p.  Each block does
// one (qb, h, b, key-chunk of <=8 tiles).  qb<8 (single chunk) writes final
// bf16 y directly; else fp32 partials [64q x 64d + 64 lsum] go to ws and
// attn_reduce sums & normalizes.
#define ATTN_SLOTS 80           // sum over qb of ceil((qb+1)/8)
#define ATTN_SLOT_F 4160        // 64*64 O + 64 lsum floats

__global__ __launch_bounds__(256)
void attention_chunk(const short* __restrict__ qkv, short* __restrict__ y,
                     float* __restrict__ part) {
  constexpr int T = 2048, C = 1024, HD = 64, S3 = 3072;
  __shared__ short Ks[64 * 72];      // [key][d], pad 72
  __shared__ short Vt[64 * 72];      // [d][key], pad 72
  __shared__ short Ps[4][16 * 72];   // per-wave P: [q][key]
  const int x = blockIdx.x, h = blockIdx.y, b = blockIdx.z;
  int qb, ch;
  if (x < 8)       { qb = x;                 ch = 0; }
  else if (x < 24) { qb = 8 + ((x - 8) >> 1);  ch = (x - 8) & 1; }
  else if (x < 48) { qb = 16 + (x - 24) / 3;   ch = (x - 24) % 3; }
  else             { qb = 24 + ((x - 48) >> 2); ch = (x - 48) & 3; }
  const int kt0 = ch * 8;
  const int kt1 = min(kt0 + 8, qb + 1);
  const int tid = threadIdx.x, wid = tid >> 6, lane = tid & 63;
  const int quad = lane >> 4, l15 = lane & 15;
  const size_t base = (size_t)b * T * S3;
  const int q0 = qb * 64 + wid * 16;
  // Q A-frags: A[m=lane&15][k=quad*8+j]
  const short* Qp = qkv + base + (size_t)(q0 + l15) * S3 + h * HD;
  const shortx8 qf0 = *(const shortx8*)(Qp + quad * 8);
  const shortx8 qf1 = *(const shortx8*)(Qp + 32 + quad * 8);
  floatx4 o[4] = {};
  float lsum[4] = {0.f, 0.f, 0.f, 0.f};
  const float scale2 = 0.03125f * 1.44269504088896f;  // 1/sqrt(C) * log2(e)
  const int skey = tid >> 2, sd = (tid & 3) * 16;  // K staging
  const int vkp = tid & 31, vdb = tid >> 5;        // V staging (vdb 0..7)
  const short* Kbase = qkv + base + C + h * HD;
  const short* Vbase = qkv + base + 2 * C + h * HD;
  // register prefetch of tile kt0
  shortx8 pk0, pk1, pv0, pv1;
  {
    const short* Kp = Kbase + (size_t)(kt0 * 64 + skey) * S3 + sd;
    pk0 = *(const shortx8*)Kp;
    pk1 = *(const shortx8*)(Kp + 8);
    const short* Vp = Vbase + (size_t)(kt0 * 64 + 2 * vkp) * S3 + vdb * 8;
    pv0 = *(const shortx8*)Vp;
    pv1 = *(const shortx8*)(Vp + S3);
  }
  for (int kt = kt0; kt < kt1; ++kt) {
    const int key0 = kt * 64;
    __syncthreads();
    *(shortx8*)&Ks[skey * 72 + sd] = pk0;
    *(shortx8*)&Ks[skey * 72 + sd + 8] = pk1;
#pragma unroll
    for (int j = 0; j < 8; ++j) {
      short2 pr = make_short2(pv0[j], pv1[j]);
      *(short2*)&Vt[(vdb * 8 + j) * 72 + 2 * vkp] = pr;
    }
    __syncthreads();
    if (kt + 1 < kt1) {  // prefetch next tile
      const int kn = key0 + 64;
      const short* Kp = Kbase + (size_t)(kn + skey) * S3 + sd;
      pk0 = *(const shortx8*)Kp;
      pk1 = *(const shortx8*)(Kp + 8);
      const short* Vp = Vbase + (size_t)(kn + 2 * vkp) * S3 + vdb * 8;
      pv0 = *(const shortx8*)Vp;
      pv1 = *(const shortx8*)(Vp + S3);
    }
    floatx4 s[4];
#pragma unroll
    for (int nt = 0; nt < 4; ++nt) {
      const short* kb = &Ks[(nt * 16 + l15) * 72 + quad * 8];
      floatx4 a = {};
      a = __builtin_amdgcn_mfma_f32_16x16x32_bf16(qf0, *(const shortx8*)kb, a, 0, 0, 0);
      a = __builtin_amdgcn_mfma_f32_16x16x32_bf16(qf1, *(const shortx8*)(kb + 32), a, 0, 0, 0);
      s[nt] = a;
    }
    short* pw = &Ps[wid][0];
    const bool diag = (kt == qb);
#pragma unroll
    for (int nt = 0; nt < 4; ++nt)
#pragma unroll
      for (int r = 0; r < 4; ++r) {
        float sv = s[nt][r] * scale2;
        if (diag) {
          const int key = key0 + nt * 16 + l15;
          const int q = q0 + quad * 4 + r;
          if (key > q) sv = -INFINITY;
        }
        const float p = exp2f(sv);
        lsum[r] += p;
        pw[(quad * 4 + r) * 72 + nt * 16 + l15] = f2bf(p);
      }
    asm volatile("s_waitcnt lgkmcnt(0)" ::: "memory");
#pragma unroll
    for (int kf = 0; kf < 2; ++kf) {
      const shortx8 pa = *(const shortx8*)&Ps[wid][l15 * 72 + kf * 32 + quad * 8];
#pragma unroll
      for (int dt = 0; dt < 4; ++dt) {
        const shortx8 vb = *(const shortx8*)&Vt[(dt * 16 + l15) * 72 + kf * 32 + quad * 8];
        o[dt] = __builtin_amdgcn_mfma_f32_16x16x32_bf16(pa, vb, o[dt], 0, 0, 0);
      }
    }
  }
  // reduce lsum over the 16 lanes of each quad group
  float ls[4];
#pragma unroll
  for (int r = 0; r < 4; ++r) {
    float s = lsum[r];
    for (int off = 1; off < 16; off <<= 1) s += __shfl_xor(s, off);
    ls[r] = s;
  }
  if (x < 8) {  // single chunk -> final output
#pragma unroll
    for (int dt = 0; dt < 4; ++dt)
#pragma unroll
      for (int r = 0; r < 4; ++r) {
        const int q = q0 + quad * 4 + r;
        y[((size_t)b * T + q) * C + h * HD + dt * 16 + l15] =
            f2bf(o[dt][r] / ls[r]);
      }
  } else {      // fp32 partials
    float* pp = part + ((size_t)(b * 16 + h) * ATTN_SLOTS + x) * ATTN_SLOT_F;
    const int qw = wid * 16;
#pragma unroll
    for (int dt = 0; dt < 4; ++dt)
#pragma unroll
      for (int r = 0; r < 4; ++r)
        pp[(qw + quad * 4 + r) * 64 + dt * 16 + l15] = o[dt][r];
    if (l15 == 0)
#pragma unroll
      for (int r = 0; r < 4; ++r)
        pp[4096 + qw + quad * 4 + r] = ls[r];
  }
}

__global__ __launch_bounds__(256)
void attn_reduce(const float* __restrict__ part, short* __restrict__ y) {
  constexpr int T = 2048, C = 1024;
  const int qb = 8 + blockIdx.x, h = blockIdx.y, b = blockIdx.z;
  const int c = qb / 8 + 1;  // 2..4 chunks
  int slot0;
  if (qb < 16)      slot0 = 8 + 2 * (qb - 8);
  else if (qb < 24) slot0 = 24 + 3 * (qb - 16);
  else              slot0 = 48 + 4 * (qb - 24);
  const float* rb = part + ((size_t)(b * 16 + h) * ATTN_SLOTS + slot0) * ATTN_SLOT_F;
  const int t = threadIdx.x;
  const int q = t >> 2, dg = (t & 3) * 16;
  float acc[16] = {};
  float ls = 0.f;
  for (int ci = 0; ci < c; ++ci) {
    const float* pp = rb + (size_t)ci * ATTN_SLOT_F;
    const float4* op = (const float4*)(pp + q * 64 + dg);
#pragma unroll
    for (int i = 0; i < 4; ++i) {
      float4 v = op[i];
      acc[4 * i + 0] += v.x; acc[4 * i + 1] += v.y;
      acc[4 * i + 2] += v.z; acc[4 * i + 3] += v.w;
    }
    ls += pp[4096 + q];
  }
  const float inv = 1.0f / ls;
  short o16[16];
#pragma unroll
  for (int i = 0; i < 16; ++i) o16[i] = f2bf(acc[i] * inv);
  short* yp = y + ((size_t)b * T + qb * 64 + q) * C + h * 64 + dg;
  *(shortx8*)yp = *(shortx8*)&o16[0];
  *(shortx8*)(yp + 8) = *(shortx8*)&o16[8];
}

// ---- fallback single-pass attention (used only if ws too small) ----
__global__ __launch_bounds__(256)
void attention_kernel(const short* __restrict__ qkv, short* __restrict__ y) {
  constexpr int T = 2048, C = 1024, HD = 64, S3 = 3072;
  __shared__ short Ks[64 * 72];
  __shared__ short Vt[64 * 72];
  __shared__ short Ps[4][16 * 72];
  const int qb = blockIdx.x, h = blockIdx.y, b = blockIdx.z;
  const int tid = threadIdx.x, wid = tid >> 6, lane = tid & 63;
  const int quad = lane >> 4, l15 = lane & 15;
  const size_t base = (size_t)b * T * S3;
  const int q0 = qb * 64 + wid * 16;
  const short* Qp = qkv + base + (size_t)(q0 + l15) * S3 + h * HD;
  const shortx8 qf0 = *(const shortx8*)(Qp + quad * 8);
  const shortx8 qf1 = *(const shortx8*)(Qp + 32 + quad * 8);
  floatx4 o[4] = {};
  float lsum[4] = {0.f, 0.f, 0.f, 0.f};
  const float scale2 = 0.03125f * 1.44269504088896f;
  const int skey = tid >> 2, sd = (tid & 3) * 16;
  const int vkp = tid & 31, vdb = tid >> 5;
  for (int kt = 0; kt <= qb; ++kt) {
    const int key0 = kt * 64;
    __syncthreads();
    {
      const short* Kp = qkv + base + (size_t)(key0 + skey) * S3 + C + h * HD + sd;
      shortx8 ka = *(const shortx8*)Kp;
      shortx8 kb = *(const shortx8*)(Kp + 8);
      *(shortx8*)&Ks[skey * 72 + sd] = ka;
      *(shortx8*)&Ks[skey * 72 + sd + 8] = kb;
      const short* Vp = qkv + base + (size_t)(key0 + 2 * vkp) * S3 + 2 * C + h * HD + vdb * 8;
      shortx8 va = *(const shortx8*)Vp;
      shortx8 vb = *(const shortx8*)(Vp + S3);
#pragma unroll
      for (int j = 0; j < 8; ++j) {
        short2 pr = make_short2(va[j], vb[j]);
        *(short2*)&Vt[(vdb * 8 + j) * 72 + 2 * vkp] = pr;
      }
    }
    __syncthreads();
    floatx4 s[4];
#pragma unroll
    for (int nt = 0; nt < 4; ++nt) {
      const short* kb = &Ks[(nt * 16 + l15) * 72 + quad * 8];
      floatx4 a = {};
      a = __builtin_amdgcn_mfma_f32_16x16x32_bf16(qf0, *(const shortx8*)kb, a, 0, 0, 0);
      a = __builtin_amdgcn_mfma_f32_16x16x32_bf16(qf1, *(const shortx8*)(kb + 32), a, 0, 0, 0);
      s[nt] = a;
    }
    short* pw = &Ps[wid][0];
    const bool diag = (kt == qb);
#pragma unroll
    for (int nt = 0; nt < 4; ++nt)
#pragma unroll
      for (int r = 0; r < 4; ++r) {
        float sv = s[nt][r] * scale2;
        if (diag) {
          const int key = key0 + nt * 16 + l15;
          const int q = q0 + quad * 4 + r;
          if (key > q) sv = -INFINITY;
        }
        const float p = exp2f(sv);
        lsum[r] += p;
        pw[(quad * 4 + r) * 72 + nt * 16 + l15] = f2bf(p);
      }
    asm volatile("s_waitcnt lgkmcnt(0)" ::: "memory");
#pragma unroll
    for (int kf = 0; kf < 2; ++kf) {
      const shortx8 pa = *(const shortx8*)&Ps[wid][l15 * 72 + kf * 32 + quad * 8];
#pragma unroll
      for (int dt = 0; dt < 4; ++dt) {
        const shortx8 vb = *(const shortx8*)&Vt[(dt * 16 + l15) * 72 + kf * 32 + quad * 8];
        o[dt] = __builtin_amdgcn_mfma_f32_16x16x32_bf16(pa, vb, o[dt], 0, 0, 0);
      }
    }
  }
  float inv[4];
#pragma unroll
  for (int r = 0; r < 4; ++r) {
    float s = lsum[r];
    for (int off = 1; off < 16; off <<= 1) s += __shfl_xor(s, off);
    inv[r] = 1.0f / s;
  }
#pragma unroll
  for (int dt = 0; dt < 4; ++dt)
#pragma unroll
    for (int r = 0; r < 4; ++r) {
      const int q = q0 + quad * 4 + r;
      y[((size_t)b * T + q) * C + h * HD + dt * 16 + l15] = f2bf(o[dt][r] * inv[r]);
    }
}

extern "C" void kernel_launch(void* const* d_in, const int* in_sizes, int n_in,
                              void* d_out, int out_size, void* d_ws, size_t ws_size,
                              hipStream_t stream) {
  const float* x      = (const float*)d_in[0];
  const float* ln1_w  = (const float*)d_in[1];
  const float* ln1_b  = (const float*)d_in[2];
  const float* qkv_w  = (const float*)d_in[3];
  const float* qkv_b  = (const float*)d_in[4];
  const float* proj_w = (const float*)d_in[5];
  const float* proj_b = (const float*)d_in[6];
  const float* ln2_w  = (const float*)d_in[7];
  const float* ln2_b  = (const float*)d_in[8];
  const float* ff_w1  = (const float*)d_in[9];
  const float* ff_b1  = (const float*)d_in[10];
  const float* ff_w2  = (const float*)d_in[11];
  const float* ff_b2  = (const float*)d_in[12];
  float* out = (float*)d_out;

  char* p = (char*)d_ws;
  short* wT_qkv  = (short*)p; p += (size_t)3072 * 1024 * 2;
  short* wT_proj = (short*)p; p += (size_t)1024 * 1024 * 2;
  short* wT_ff1  = (short*)p; p += (size_t)4096 * 1024 * 2;
  short* wT_ff2  = (short*)p; p += (size_t)1024 * 4096 * 2;
  short* act16   = (short*)p; p += (size_t)8192 * 1024 * 2;  // h -> y -> h2
  short* big     = (short*)p; p += (size_t)8192 * 4096 * 2;  // qkv -> ff act
  float* part    = (float*)p;  // attn partials (85 MB), later reused for ff2
  const size_t need = (size_t)(p - (char*)d_ws) +
                      (size_t)64 * ATTN_SLOTS * ATTN_SLOT_F * 4;
  const bool split = (ws_size >= need);

  // weights -> bf16 transposed [N][K]
  transpose_cast<<<dim3(96, 32), 256, 0, stream>>>(qkv_w, wT_qkv, 1024, 3072);
  transpose_cast<<<dim3(32, 32), 256, 0, stream>>>(proj_w, wT_proj, 1024, 1024);
  transpose_cast<<<dim3(128, 32), 256, 0, stream>>>(ff_w1, wT_ff1, 1024, 4096);
  transpose_cast<<<dim3(32, 128), 256, 0, stream>>>(ff_w2, wT_ff2, 4096, 1024);

  // h = LN1(x)
  layernorm_kernel<<<8192, 256, 0, stream>>>(x, ln1_w, ln1_b, act16);
  // qkv = h @ qkv_w + qkv_b           [8192,3072]
  gemm_bt<0, short><<<dim3(24, 64), 256, 0, stream>>>(
      act16, 1024, wT_qkv, 1024, qkv_b, nullptr, big, 8192, 3072, 1024);
  // y = causal_attention(qkv)  — split-K if ws fits, else single-pass
  if (split) {
    attention_chunk<<<dim3(ATTN_SLOTS, 16, 4), 256, 0, stream>>>(big, act16, part);
    attn_reduce<<<dim3(24, 16, 4), 256, 0, stream>>>(part, act16);
  } else {
    attention_kernel<<<dim3(32, 16, 4), 256, 0, stream>>>(big, act16);
  }
  // x2 = x + y @ proj_w + proj_b  -> d_out (fp32)
  gemm_bt<2, float><<<dim3(8, 64), 256, 0, stream>>>(
      act16, 1024, wT_proj, 1024, proj_b, x, out, 8192, 1024, 1024);
  // h2 = LN2(x2)
  layernorm_kernel<<<8192, 256, 0, stream>>>(out, ln2_w, ln2_b, act16);
  // a = relu(h2 @ ff_w1 + ff_b1)      [8192,4096]
  gemm_bt<1, short><<<dim3(32, 64), 256, 0, stream>>>(
      act16, 1024, wT_ff1, 1024, ff_b1, nullptr, big, 8192, 4096, 1024);
  // out = x2 + a @ ff_w2 + ff_b2
  if (split) {
    // split-K by 2: grid z = K-slice; fp32 partials into attn's (now dead)
    // part region; reduce fuses +bias +resid (out holds x2).
    gemm_bt<4, float><<<dim3(8, 64, 2), 256, 0, stream>>>(
        big, 4096, wT_ff2, 4096, nullptr, nullptr, part, 8192, 1024, 2048);
    ff2_reduce<<<8192, 256, 0, stream>>>(part, ff_b2, out);
  } else {
    gemm_bt<2, float><<<dim3(8, 64), 256, 0, stream>>>(
        big, 4096, wT_ff2, 4096, ff_b2, out, out, 8192, 1024, 4096);
  }
}

// Round 6
// 573.922 us; speedup vs baseline: 1.0508x; 1.0508x over previous
//
#include <hip/hip_runtime.h>

// Decoder block: x -> LN1 -> QKV GEMM -> causal MHA -> proj(+x) -> LN2 -> FFN(+res)
// B=4 T=2048 C=1024 H=16 hd=64.  All MFMA compute in bf16, fp32 accumulate.

typedef __attribute__((ext_vector_type(8))) short shortx8;   // 8 bf16 (4 VGPR)
typedef __attribute__((ext_vector_type(4))) float floatx4;   // MFMA C/D

__device__ __forceinline__ short f2bf(float f) {
  unsigned u = __builtin_bit_cast(unsigned, f);
  u = (u + 0x7fffu + ((u >> 16) & 1u)) >> 16;   // RNE
  return (short)u;
}

// ---- weight transpose + cast: in [K][N] f32 -> out [N][K] bf16 ----
__global__ __launch_bounds__(256)
void transpose_cast(const float* __restrict__ in, short* __restrict__ out,
                    int K, int N) {
  __shared__ float tile[32][33];
  const int n0 = blockIdx.x * 32, k0 = blockIdx.y * 32;
  const int tx = threadIdx.x & 31, ty = threadIdx.x >> 5;  // 32x8
  for (int i = 0; i < 32; i += 8)
    tile[ty + i][tx] = in[(size_t)(k0 + ty + i) * N + n0 + tx];
  __syncthreads();
  for (int i = 0; i < 32; i += 8)
    out[(size_t)(n0 + ty + i) * K + k0 + tx] = f2bf(tile[tx][ty + i]);
}

// ---- layernorm: f32 in -> bf16 out, C=1024, one block (256 thr) per row ----
__global__ __launch_bounds__(256)
void layernorm_kernel(const float* __restrict__ x, const float* __restrict__ w,
                      const float* __restrict__ bta, short* __restrict__ out) {
  const int C = 1024;
  const int row = blockIdx.x;
  const float4 v = ((const float4*)(x + (size_t)row * C))[threadIdx.x];
  float s1 = v.x + v.y + v.z + v.w;
  float s2 = v.x * v.x + v.y * v.y + v.z * v.z + v.w * v.w;
  for (int m = 1; m < 64; m <<= 1) { s1 += __shfl_xor(s1, m); s2 += __shfl_xor(s2, m); }
  __shared__ float r1[4], r2[4];
  const int wid = threadIdx.x >> 6, lane = threadIdx.x & 63;
  if (lane == 0) { r1[wid] = s1; r2[wid] = s2; }
  __syncthreads();
  s1 = r1[0] + r1[1] + r1[2] + r1[3];
  s2 = r2[0] + r2[1] + r2[2] + r2[3];
  const float mean = s1 * (1.0f / C);
  const float var = s2 * (1.0f / C) - mean * mean;
  const float rs = rsqrtf(var + 1e-5f);
  const float4 wv = ((const float4*)w)[threadIdx.x];
  const float4 bv = ((const float4*)bta)[threadIdx.x];
  short4 o;
  o.x = f2bf((v.x - mean) * rs * wv.x + bv.x);
  o.y = f2bf((v.y - mean) * rs * wv.y + bv.y);
  o.z = f2bf((v.z - mean) * rs * wv.z + bv.z);
  o.w = f2bf((v.w - mean) * rs * wv.w + bv.w);
  *(short4*)(out + (size_t)row * C + threadIdx.x * 4) = o;
}

// ---- MFMA GEMM: C = A[M,K]@Bt[N,K]^T + bias (+resid)(+relu)
// 128x128 tile, BK=32, 4 waves of 64x64, global_load_lds width=16 staging.
// XCD row-band swizzle: consecutive flat block ids round-robin XCDs (g%8);
// map so each XCD owns mb/8 contiguous row-tiles and sweeps columns within
// the band -> each A row-tile is fetched by exactly ONE XCD's L2 (R5: A was
// pulled ~3x over the fabric, 292 MB vs 104 MB compulsory on ff2).
// FLAGS: bit0=relu, bit1=resid(fp32).  lda/ldb = row strides of A / Bt.
template<int FLAGS, typename OutT>
__global__ __launch_bounds__(256)
void gemm_bt(const short* __restrict__ A, int lda,
             const short* __restrict__ Bt, int ldb,
             const float* __restrict__ bias, const float* __restrict__ resid,
             OutT* __restrict__ C, int M, int N, int K) {
  constexpr bool RELU = (FLAGS & 1) != 0;
  constexpr bool RESID = (FLAGS & 2) != 0;
  __shared__ short As[128 * 32];   // [m][k]
  __shared__ short Bs[128 * 32];   // [n][k]
  int bmi, bni;
  {
    const int nb = gridDim.x, mb = gridDim.y;
    const int g = blockIdx.x + nb * blockIdx.y;
    if ((mb & 7) == 0) {
      const int xcd = g & 7, l = g >> 3;      // 8 XCDs, round-robin dispatch
      bmi = xcd * (mb >> 3) + l / nb;
      bni = l % nb;
    } else { bmi = blockIdx.y; bni = blockIdx.x; }
  }
  const int bm0 = bmi * 128, bn0 = bni * 128;
  const int tid = threadIdx.x, wid = tid >> 6, lane = tid & 63;
  const int quad = lane >> 4, l15 = lane & 15;
  const int wm = wid & 1, wn = wid >> 1;
  const int srow = lane >> 2, scol = (lane & 3) * 8;
  floatx4 acc[4][4] = {};
  for (int k0 = 0; k0 < K; k0 += 32) {
    for (int i = 0; i < 2; ++i) {
      const int r0 = (wid * 2 + i) * 16;
      const short* ga = A + (size_t)(bm0 + r0 + srow) * lda + k0 + scol;
      const short* gb = Bt + (size_t)(bn0 + r0 + srow) * ldb + k0 + scol;
      __builtin_amdgcn_global_load_lds(
          (const __attribute__((address_space(1))) void*)ga,
          (__attribute__((address_space(3))) void*)&As[r0 * 32], 16, 0, 0);
      __builtin_amdgcn_global_load_lds(
          (const __attribute__((address_space(1))) void*)gb,
          (__attribute__((address_space(3))) void*)&Bs[r0 * 32], 16, 0, 0);
    }
    asm volatile("s_waitcnt vmcnt(0)" ::: "memory");
    __syncthreads();
    shortx8 af[4], bfr[4];
#pragma unroll
    for (int i = 0; i < 4; ++i)
      af[i] = *(const shortx8*)&As[(wm * 64 + i * 16 + l15) * 32 + quad * 8];
#pragma unroll
    for (int j = 0; j < 4; ++j)
      bfr[j] = *(const shortx8*)&Bs[(wn * 64 + j * 16 + l15) * 32 + quad * 8];
#pragma unroll
    for (int i = 0; i < 4; ++i)
#pragma unroll
      for (int j = 0; j < 4; ++j)
        acc[i][j] = __builtin_amdgcn_mfma_f32_16x16x32_bf16(af[i], bfr[j], acc[i][j], 0, 0, 0);
    __syncthreads();
  }
  // epilogue: D row = (lane>>4)*4 + reg, col = lane&15 (m89/m91-verified)
#pragma unroll
  for (int i = 0; i < 4; ++i) {
    const int row = bm0 + wm * 64 + i * 16 + quad * 4;
#pragma unroll
    for (int j = 0; j < 4; ++j) {
      const int col = bn0 + wn * 64 + j * 16 + l15;
      const float bb = bias[col];
#pragma unroll
      for (int r = 0; r < 4; ++r) {
        float v = acc[i][j][r] + bb;
        if (RELU) v = fmaxf(v, 0.0f);
        if (RESID) v += resid[(size_t)(row + r) * N + col];
        if constexpr (sizeof(OutT) == 2)
          C[(size_t)(row + r) * N + col] = f2bf(v);
        else
          C[(size_t)(row + r) * N + col] = v;
      }
    }
  }
}

// ================= split-K flash attention =================
// Static-max softmax (scores = q.k/32, tiny; fp32 exp2 has huge headroom) makes
// chunk partials ADDITIVE: O_unnorm = sum P.V, lsum = sum p.  Each block does
// one (qb, h, b, key-chunk of <=8 tiles).  qb<8 (single chunk) writes final
// bf16 y directly; else fp32 partials [64q x 64d + 64 lsum] go to ws and
// attn_reduce sums & normalizes.
#define ATTN_SLOTS 80           // sum over qb of ceil((qb+1)/8)
#define ATTN_SLOT_F 4160        // 64*64 O + 64 lsum floats

__global__ __launch_bounds__(256)
void attention_chunk(const short* __restrict__ qkv, short* __restrict__ y,
                     float* __restrict__ part) {
  constexpr int T = 2048, C = 1024, HD = 64, S3 = 3072;
  __shared__ short Ks[64 * 72];      // [key][d], pad 72
  __shared__ short Vt[64 * 72];      // [d][key], pad 72
  __shared__ short Ps[4][16 * 72];   // per-wave P: [q][key]
  const int x = blockIdx.x, h = blockIdx.y, b = blockIdx.z;
  int qb, ch;
  if (x < 8)       { qb = x;                 ch = 0; }
  else if (x < 24) { qb = 8 + ((x - 8) >> 1);  ch = (x - 8) & 1; }
  else if (x < 48) { qb = 16 + (x - 24) / 3;   ch = (x - 24) % 3; }
  else             { qb = 24 + ((x - 48) >> 2); ch = (x - 48) & 3; }
  const int kt0 = ch * 8;
  const int kt1 = min(kt0 + 8, qb + 1);
  const int tid = threadIdx.x, wid = tid >> 6, lane = tid & 63;
  const int quad = lane >> 4, l15 = lane & 15;
  const size_t base = (size_t)b * T * S3;
  const int q0 = qb * 64 + wid * 16;
  // Q A-frags: A[m=lane&15][k=quad*8+j]
  const short* Qp = qkv + base + (size_t)(q0 + l15) * S3 + h * HD;
  const shortx8 qf0 = *(const shortx8*)(Qp + quad * 8);
  const shortx8 qf1 = *(const shortx8*)(Qp + 32 + quad * 8);
  floatx4 o[4] = {};
  float lsum[4] = {0.f, 0.f, 0.f, 0.f};
  const float scale2 = 0.03125f * 1.44269504088896f;  // 1/sqrt(C) * log2(e)
  const int skey = tid >> 2, sd = (tid & 3) * 16;  // K staging
  const int vkp = tid & 31, vdb = tid >> 5;        // V staging (vdb 0..7)
  const short* Kbase = qkv + base + C + h * HD;
  const short* Vbase = qkv + base + 2 * C + h * HD;
  // register prefetch of tile kt0
  shortx8 pk0, pk1, pv0, pv1;
  {
    const short* Kp = Kbase + (size_t)(kt0 * 64 + skey) * S3 + sd;
    pk0 = *(const shortx8*)Kp;
    pk1 = *(const shortx8*)(Kp + 8);
    const short* Vp = Vbase + (size_t)(kt0 * 64 + 2 * vkp) * S3 + vdb * 8;
    pv0 = *(const shortx8*)Vp;
    pv1 = *(const shortx8*)(Vp + S3);
  }
  for (int kt = kt0; kt < kt1; ++kt) {
    const int key0 = kt * 64;
    __syncthreads();
    *(shortx8*)&Ks[skey * 72 + sd] = pk0;
    *(shortx8*)&Ks[skey * 72 + sd + 8] = pk1;
#pragma unroll
    for (int j = 0; j < 8; ++j) {
      short2 pr = make_short2(pv0[j], pv1[j]);
      *(short2*)&Vt[(vdb * 8 + j) * 72 + 2 * vkp] = pr;
    }
    __syncthreads();
    if (kt + 1 < kt1) {  // prefetch next tile
      const int kn = key0 + 64;
      const short* Kp = Kbase + (size_t)(kn + skey) * S3 + sd;
      pk0 = *(const shortx8*)Kp;
      pk1 = *(const shortx8*)(Kp + 8);
      const short* Vp = Vbase + (size_t)(kn + 2 * vkp) * S3 + vdb * 8;
      pv0 = *(const shortx8*)Vp;
      pv1 = *(const shortx8*)(Vp + S3);
    }
    floatx4 s[4];
#pragma unroll
    for (int nt = 0; nt < 4; ++nt) {
      const short* kb = &Ks[(nt * 16 + l15) * 72 + quad * 8];
      floatx4 a = {};
      a = __builtin_amdgcn_mfma_f32_16x16x32_bf16(qf0, *(const shortx8*)kb, a, 0, 0, 0);
      a = __builtin_amdgcn_mfma_f32_16x16x32_bf16(qf1, *(const shortx8*)(kb + 32), a, 0, 0, 0);
      s[nt] = a;
    }
    short* pw = &Ps[wid][0];
    const bool diag = (kt == qb);
#pragma unroll
    for (int nt = 0; nt < 4; ++nt)
#pragma unroll
      for (int r = 0; r < 4; ++r) {
        float sv = s[nt][r] * scale2;
        if (diag) {
          const int key = key0 + nt * 16 + l15;
          const int q = q0 + quad * 4 + r;
          if (key > q) sv = -INFINITY;
        }
        const float p = exp2f(sv);
        lsum[r] += p;
        pw[(quad * 4 + r) * 72 + nt * 16 + l15] = f2bf(p);
      }
    asm volatile("s_waitcnt lgkmcnt(0)" ::: "memory");
#pragma unroll
    for (int kf = 0; kf < 2; ++kf) {
      const shortx8 pa = *(const shortx8*)&Ps[wid][l15 * 72 + kf * 32 + quad * 8];
#pragma unroll
      for (int dt = 0; dt < 4; ++dt) {
        const shortx8 vb = *(const shortx8*)&Vt[(dt * 16 + l15) * 72 + kf * 32 + quad * 8];
        o[dt] = __builtin_amdgcn_mfma_f32_16x16x32_bf16(pa, vb, o[dt], 0, 0, 0);
      }
    }
  }
  // reduce lsum over the 16 lanes of each quad group
  float ls[4];
#pragma unroll
  for (int r = 0; r < 4; ++r) {
    float s = lsum[r];
    for (int off = 1; off < 16; off <<= 1) s += __shfl_xor(s, off);
    ls[r] = s;
  }
  if (x < 8) {  // single chunk -> final output
#pragma unroll
    for (int dt = 0; dt < 4; ++dt)
#pragma unroll
      for (int r = 0; r < 4; ++r) {
        const int q = q0 + quad * 4 + r;
        y[((size_t)b * T + q) * C + h * HD + dt * 16 + l15] =
            f2bf(o[dt][r] / ls[r]);
      }
  } else {      // fp32 partials
    float* pp = part + ((size_t)(b * 16 + h) * ATTN_SLOTS + x) * ATTN_SLOT_F;
    const int qw = wid * 16;
#pragma unroll
    for (int dt = 0; dt < 4; ++dt)
#pragma unroll
      for (int r = 0; r < 4; ++r)
        pp[(qw + quad * 4 + r) * 64 + dt * 16 + l15] = o[dt][r];
    if (l15 == 0)
#pragma unroll
      for (int r = 0; r < 4; ++r)
        pp[4096 + qw + quad * 4 + r] = ls[r];
  }
}

__global__ __launch_bounds__(256)
void attn_reduce(const float* __restrict__ part, short* __restrict__ y) {
  constexpr int T = 2048, C = 1024;
  const int qb = 8 + blockIdx.x, h = blockIdx.y, b = blockIdx.z;
  const int c = qb / 8 + 1;  // 2..4 chunks
  int slot0;
  if (qb < 16)      slot0 = 8 + 2 * (qb - 8);
  else if (qb < 24) slot0 = 24 + 3 * (qb - 16);
  else              slot0 = 48 + 4 * (qb - 24);
  const float* rb = part + ((size_t)(b * 16 + h) * ATTN_SLOTS + slot0) * ATTN_SLOT_F;
  const int t = threadIdx.x;
  const int q = t >> 2, dg = (t & 3) * 16;
  float acc[16] = {};
  float ls = 0.f;
  for (int ci = 0; ci < c; ++ci) {
    const float* pp = rb + (size_t)ci * ATTN_SLOT_F;
    const float4* op = (const float4*)(pp + q * 64 + dg);
#pragma unroll
    for (int i = 0; i < 4; ++i) {
      float4 v = op[i];
      acc[4 * i + 0] += v.x; acc[4 * i + 1] += v.y;
      acc[4 * i + 2] += v.z; acc[4 * i + 3] += v.w;
    }
    ls += pp[4096 + q];
  }
  const float inv = 1.0f / ls;
  short o16[16];
#pragma unroll
  for (int i = 0; i < 16; ++i) o16[i] = f2bf(acc[i] * inv);
  short* yp = y + ((size_t)b * T + qb * 64 + q) * C + h * 64 + dg;
  *(shortx8*)yp = *(shortx8*)&o16[0];
  *(shortx8*)(yp + 8) = *(shortx8*)&o16[8];
}

// ---- fallback single-pass attention (used only if ws too small) ----
__global__ __launch_bounds__(256)
void attention_kernel(const short* __restrict__ qkv, short* __restrict__ y) {
  constexpr int T = 2048, C = 1024, HD = 64, S3 = 3072;
  __shared__ short Ks[64 * 72];
  __shared__ short Vt[64 * 72];
  __shared__ short Ps[4][16 * 72];
  const int qb = blockIdx.x, h = blockIdx.y, b = blockIdx.z;
  const int tid = threadIdx.x, wid = tid >> 6, lane = tid & 63;
  const int quad = lane >> 4, l15 = lane & 15;
  const size_t base = (size_t)b * T * S3;
  const int q0 = qb * 64 + wid * 16;
  const short* Qp = qkv + base + (size_t)(q0 + l15) * S3 + h * HD;
  const shortx8 qf0 = *(const shortx8*)(Qp + quad * 8);
  const shortx8 qf1 = *(const shortx8*)(Qp + 32 + quad * 8);
  floatx4 o[4] = {};
  float lsum[4] = {0.f, 0.f, 0.f, 0.f};
  const float scale2 = 0.03125f * 1.44269504088896f;
  const int skey = tid >> 2, sd = (tid & 3) * 16;
  const int vkp = tid & 31, vdb = tid >> 5;
  for (int kt = 0; kt <= qb; ++kt) {
    const int key0 = kt * 64;
    __syncthreads();
    {
      const short* Kp = qkv + base + (size_t)(key0 + skey) * S3 + C + h * HD + sd;
      shortx8 ka = *(const shortx8*)Kp;
      shortx8 kb = *(const shortx8*)(Kp + 8);
      *(shortx8*)&Ks[skey * 72 + sd] = ka;
      *(shortx8*)&Ks[skey * 72 + sd + 8] = kb;
      const short* Vp = qkv + base + (size_t)(key0 + 2 * vkp) * S3 + 2 * C + h * HD + vdb * 8;
      shortx8 va = *(const shortx8*)Vp;
      shortx8 vb = *(const shortx8*)(Vp + S3);
#pragma unroll
      for (int j = 0; j < 8; ++j) {
        short2 pr = make_short2(va[j], vb[j]);
        *(short2*)&Vt[(vdb * 8 + j) * 72 + 2 * vkp] = pr;
      }
    }
    __syncthreads();
    floatx4 s[4];
#pragma unroll
    for (int nt = 0; nt < 4; ++nt) {
      const short* kb = &Ks[(nt * 16 + l15) * 72 + quad * 8];
      floatx4 a = {};
      a = __builtin_amdgcn_mfma_f32_16x16x32_bf16(qf0, *(const shortx8*)kb, a, 0, 0, 0);
      a = __builtin_amdgcn_mfma_f32_16x16x32_bf16(qf1, *(const shortx8*)(kb + 32), a, 0, 0, 0);
      s[nt] = a;
    }
    short* pw = &Ps[wid][0];
    const bool diag = (kt == qb);
#pragma unroll
    for (int nt = 0; nt < 4; ++nt)
#pragma unroll
      for (int r = 0; r < 4; ++r) {
        float sv = s[nt][r] * scale2;
        if (diag) {
          const int key = key0 + nt * 16 + l15;
          const int q = q0 + quad * 4 + r;
          if (key > q) sv = -INFINITY;
        }
        const float p = exp2f(sv);
        lsum[r] += p;
        pw[(quad * 4 + r) * 72 + nt * 16 + l15] = f2bf(p);
      }
    asm volatile("s_waitcnt lgkmcnt(0)" ::: "memory");
#pragma unroll
    for (int kf = 0; kf < 2; ++kf) {
      const shortx8 pa = *(const shortx8*)&Ps[wid][l15 * 72 + kf * 32 + quad * 8];
#pragma unroll
      for (int dt = 0; dt < 4; ++dt) {
        const shortx8 vb = *(const shortx8*)&Vt[(dt * 16 + l15) * 72 + kf * 32 + quad * 8];
        o[dt] = __builtin_amdgcn_mfma_f32_16x16x32_bf16(pa, vb, o[dt], 0, 0, 0);
      }
    }
  }
  float inv[4];
#pragma unroll
  for (int r = 0; r < 4; ++r) {
    float s = lsum[r];
    for (int off = 1; off < 16; off <<= 1) s += __shfl_xor(s, off);
    inv[r] = 1.0f / s;
  }
#pragma unroll
  for (int dt = 0; dt < 4; ++dt)
#pragma unroll
    for (int r = 0; r < 4; ++r) {
      const int q = q0 + quad * 4 + r;
      y[((size_t)b * T + q) * C + h * HD + dt * 16 + l15] = f2bf(o[dt][r] * inv[r]);
    }
}

extern "C" void kernel_launch(void* const* d_in, const int* in_sizes, int n_in,
                              void* d_out, int out_size, void* d_ws, size_t ws_size,
                              hipStream_t stream) {
  const float* x      = (const float*)d_in[0];
  const float* ln1_w  = (const float*)d_in[1];
  const float* ln1_b  = (const float*)d_in[2];
  const float* qkv_w  = (const float*)d_in[3];
  const float* qkv_b  = (const float*)d_in[4];
  const float* proj_w = (const float*)d_in[5];
  const float* proj_b = (const float*)d_in[6];
  const float* ln2_w  = (const float*)d_in[7];
  const float* ln2_b  = (const float*)d_in[8];
  const float* ff_w1  = (const float*)d_in[9];
  const float* ff_b1  = (const float*)d_in[10];
  const float* ff_w2  = (const float*)d_in[11];
  const float* ff_b2  = (const float*)d_in[12];
  float* out = (float*)d_out;

  char* p = (char*)d_ws;
  short* wT_qkv  = (short*)p; p += (size_t)3072 * 1024 * 2;
  short* wT_proj = (short*)p; p += (size_t)1024 * 1024 * 2;
  short* wT_ff1  = (short*)p; p += (size_t)4096 * 1024 * 2;
  short* wT_ff2  = (short*)p; p += (size_t)1024 * 4096 * 2;
  short* act16   = (short*)p; p += (size_t)8192 * 1024 * 2;  // h -> y -> h2
  short* big     = (short*)p; p += (size_t)8192 * 4096 * 2;  // qkv -> ff act
  float* part    = (float*)p;  // attn partials (85 MB)
  const size_t need = (size_t)(p - (char*)d_ws) +
                      (size_t)64 * ATTN_SLOTS * ATTN_SLOT_F * 4;
  const bool split = (ws_size >= need);

  // weights -> bf16 transposed [N][K]
  transpose_cast<<<dim3(96, 32), 256, 0, stream>>>(qkv_w, wT_qkv, 1024, 3072);
  transpose_cast<<<dim3(32, 32), 256, 0, stream>>>(proj_w, wT_proj, 1024, 1024);
  transpose_cast<<<dim3(128, 32), 256, 0, stream>>>(ff_w1, wT_ff1, 1024, 4096);
  transpose_cast<<<dim3(32, 128), 256, 0, stream>>>(ff_w2, wT_ff2, 4096, 1024);

  // h = LN1(x)
  layernorm_kernel<<<8192, 256, 0, stream>>>(x, ln1_w, ln1_b, act16);
  // qkv = h @ qkv_w + qkv_b           [8192,3072]
  gemm_bt<0, short><<<dim3(24, 64), 256, 0, stream>>>(
      act16, 1024, wT_qkv, 1024, qkv_b, nullptr, big, 8192, 3072, 1024);
  // y = causal_attention(qkv)  — split-K if ws fits, else single-pass
  if (split) {
    attention_chunk<<<dim3(ATTN_SLOTS, 16, 4), 256, 0, stream>>>(big, act16, part);
    attn_reduce<<<dim3(24, 16, 4), 256, 0, stream>>>(part, act16);
  } else {
    attention_kernel<<<dim3(32, 16, 4), 256, 0, stream>>>(big, act16);
  }
  // x2 = x + y @ proj_w + proj_b  -> d_out (fp32)
  gemm_bt<2, float><<<dim3(8, 64), 256, 0, stream>>>(
      act16, 1024, wT_proj, 1024, proj_b, x, out, 8192, 1024, 1024);
  // h2 = LN2(x2)
  layernorm_kernel<<<8192, 256, 0, stream>>>(out, ln2_w, ln2_b, act16);
  // a = relu(h2 @ ff_w1 + ff_b1)      [8192,4096]
  gemm_bt<1, short><<<dim3(32, 64), 256, 0, stream>>>(
      act16, 1024, wT_ff1, 1024, ff_b1, nullptr, big, 8192, 4096, 1024);
  // out = x2 + a @ ff_w2 + ff_b2  (resid read-before-write, same thread)
  gemm_bt<2, float><<<dim3(8, 64), 256, 0, stream>>>(
      big, 4096, wT_ff2, 4096, ff_b2, out, out, 8192, 1024, 4096);
}